// Round 4
// baseline (1418.329 us; speedup 1.0000x reference)
//
#include <hip/hip_runtime.h>
#include <hip/hip_bf16.h>

// Problem: N=2048, F_IN=128, F_OUT=64
// out[j,f] = sum_{i,k} A[j,i] H[i,f] mh[i,k] H[k,f] mf[j,k],  H = X@W + b
// R4: back to R2's proven barrier/double-buffer skeleton (R3's free-running
// waves regressed). Change vs R2: B operand (mhT) bypasses LDS entirely --
// loaded global->VGPR (L2-hot slab shared by all blocks), double-buffered
// per 32-i step. LDS pipe per it drops ~2440 -> ~1300 cyc (A reads + h reads
// + A-only DMA writes), de-serializing the barrier phases.

typedef __attribute__((ext_vector_type(8))) _Float16 f16x8;
typedef __attribute__((ext_vector_type(4))) _Float16 f16x4;
typedef __attribute__((ext_vector_type(4))) float f32x4;

#define N 2048
#define FOUT 64
#define FIN 128
#define NIT 512   // 16 ktiles * 32 its of 64-i

__device__ __forceinline__ void gl_lds16(const _Float16* g, _Float16* l) {
    __builtin_amdgcn_global_load_lds(
        (const __attribute__((address_space(1))) void*)g,
        (__attribute__((address_space(3))) void*)l, 16, 0, 0);
}

// ---------------- prep kernels ----------------

__global__ __launch_bounds__(256) void k_h(const float* __restrict__ X,
                                           const float* __restrict__ W,
                                           const float* __restrict__ bias,
                                           float* __restrict__ HT,
                                           _Float16* __restrict__ HTh) {
    __shared__ float Ws[FIN * FOUT];
    __shared__ float Xs[4 * FIN];
    int t = threadIdx.x;
#pragma unroll
    for (int s = 0; s < 32; ++s) Ws[t + 256 * s] = W[t + 256 * s];
    int i0 = blockIdx.x * 4;
#pragma unroll
    for (int s = 0; s < 2; ++s) { int idx = t + 256 * s; Xs[idx] = X[(size_t)i0 * FIN + idx]; }
    __syncthreads();
    int f = t & 63, il = t >> 6;
    float h = bias[f];
#pragma unroll
    for (int p = 0; p < FIN; ++p) h = fmaf(Xs[il * FIN + p], Ws[p * FOUT + f], h);
    int i = i0 + il;
    HT[f * N + i] = h;
    HTh[f * N + i] = (_Float16)h;
}

__global__ __launch_bounds__(256) void k_a2h(const float* __restrict__ A,
                                             _Float16* __restrict__ Ah) {
    int g = blockIdx.x * 256 + threadIdx.x;
    float4 v = ((const float4*)A)[g];
    f16x4 o;
    o[0] = (_Float16)v.x; o[1] = (_Float16)v.y; o[2] = (_Float16)v.z; o[3] = (_Float16)v.w;
    ((f16x4*)Ah)[g] = o;
}

__global__ __launch_bounds__(256) void k_mht(const float* __restrict__ mh,
                                             _Float16* __restrict__ mhT) {
    __shared__ float tile[64][65];
    int t = threadIdx.x;
    int bx = blockIdx.x & 31;
    int by = blockIdx.x >> 5;
#pragma unroll
    for (int s = 0; s < 16; ++s) {
        int lin = t + 256 * s;
        int r = lin >> 6, c = lin & 63;
        tile[r][c] = mh[(size_t)(by * 64 + r) * N + bx * 64 + c];
    }
    __syncthreads();
#pragma unroll
    for (int s = 0; s < 16; ++s) {
        int lin = t + 256 * s;
        int kr = lin >> 6, ic = lin & 63;
        mhT[(size_t)(bx * 64 + kr) * N + by * 64 + ic] = (_Float16)tile[ic][kr];
    }
}

// ---------------- main kernel ----------------
// grid 512 = 16 jtiles * 32 fgroups; 256 threads; block = 128j x 128k x 2f.
// Wave w: wj=(w&1)*64, wk=(w>>1)*64.

// stage A tile for iteration it_ into la_ (4 glds calls/wave; rows w*32..+32)
#define ISSUE_A(it_, la_)                                                     \
    {                                                                         \
        int itc_ = ((it_) < NIT) ? (it_) : (NIT - 1);                         \
        int ib_ = (itc_ & 31) << 6;                                           \
        const _Float16* pa_ = Ah + aoff + ib_;                                \
        _Pragma("unroll") for (int c_ = 0; c_ < 4; ++c_)                      \
            gl_lds16(pa_ + c_ * 8 * N, (la_) + c_ * 512);                     \
    }

// load B fragments for (it_, s_) into f16x8 dst_[4] (global->VGPR, L2-hot)
#define BLOAD(dst_, it_, s_)                                                  \
    {                                                                         \
        int itc_ = ((it_) < NIT) ? (it_) : (NIT - 1);                         \
        int ib_ = ((itc_ & 31) << 6) + ((s_) << 5) + (q << 3);                \
        int kb_ = (itc_ >> 5) << 7;                                           \
        const _Float16* pb_ = mhT + (size_t)(kb_ + wk + l16) * N + ib_;       \
        _Pragma("unroll") for (int kk_ = 0; kk_ < 4; ++kk_)                   \
            dst_[kk_] = *(const f16x8*)&pb_[(size_t)(kk_ << 4) * N];          \
    }

#define COMPUTE_S(it_, s_, ta_, b_)                                           \
    {                                                                         \
        int ib_ = (((it_) & 31) << 6) + ((s_) << 5);                          \
        f16x8 ar_[4];                                                         \
        _Pragma("unroll") for (int x = 0; x < 4; ++x)                         \
            ar_[x] = *(const f16x8*)&(ta_)[(wj + x * 16 + l16) * 64 +         \
                                           ((((q + 4 * (s_)) ^ (l16 & 7))) << 3)]; \
        f16x8 h0_ = *(const f16x8*)&hbuf[0][ib_ + (q << 3)];                  \
        f16x8 h1_ = *(const f16x8*)&hbuf[1][ib_ + (q << 3)];                  \
        _Pragma("unroll") for (int jj = 0; jj < 4; ++jj) {                    \
            f16x8 a0_ = ar_[jj] * h0_;                                        \
            f16x8 a1_ = ar_[jj] * h1_;                                        \
            _Pragma("unroll") for (int kk = 0; kk < 4; ++kk) {                \
                acc[0][jj][kk] = __builtin_amdgcn_mfma_f32_16x16x32_f16(      \
                    a0_, (b_)[kk], acc[0][jj][kk], 0, 0, 0);                  \
                acc[1][jj][kk] = __builtin_amdgcn_mfma_f32_16x16x32_f16(      \
                    a1_, (b_)[kk], acc[1][jj][kk], 0, 0, 0);                  \
            }                                                                 \
        }                                                                     \
    }

#define EPILOGUE(kt_)                                                         \
    {                                                                         \
        int kbase_ = (kt_) << 7;                                              \
        _Pragma("unroll") for (int jj = 0; jj < 4; ++jj) {                    \
            float t0_[4] = {0.f, 0.f, 0.f, 0.f};                              \
            float t1_[4] = {0.f, 0.f, 0.f, 0.f};                              \
            _Pragma("unroll") for (int kk = 0; kk < 4; ++kk) {                \
                int kg_ = kbase_ + wk + kk * 16 + l16;                        \
                float hk0_ = HT[f0 * N + kg_];                                \
                float hk1_ = HT[(f0 + 1) * N + kg_];                          \
                int jrow_ = jbase + wj + jj * 16 + q * 4;                     \
                _Pragma("unroll") for (int r = 0; r < 4; ++r) {               \
                    float m_ = mf[(size_t)(jrow_ + r) * N + kg_];             \
                    t0_[r] = fmaf(acc[0][jj][kk][r], m_ * hk0_, t0_[r]);      \
                    t1_[r] = fmaf(acc[1][jj][kk][r], m_ * hk1_, t1_[r]);      \
                }                                                             \
            }                                                                 \
            _Pragma("unroll") for (int r = 0; r < 4; ++r) {                   \
                float v0_ = t0_[r], v1_ = t1_[r];                             \
                v0_ += __shfl_xor(v0_, 1); v1_ += __shfl_xor(v1_, 1);         \
                v0_ += __shfl_xor(v0_, 2); v1_ += __shfl_xor(v1_, 2);         \
                v0_ += __shfl_xor(v0_, 4); v1_ += __shfl_xor(v1_, 4);         \
                v0_ += __shfl_xor(v0_, 8); v1_ += __shfl_xor(v1_, 8);         \
                outp[0][jj][r] += v0_;                                        \
                outp[1][jj][r] += v1_;                                        \
            }                                                                 \
        }                                                                     \
        _Pragma("unroll") for (int a_ = 0; a_ < 2; ++a_)                      \
            _Pragma("unroll") for (int b_ = 0; b_ < 4; ++b_)                  \
                _Pragma("unroll") for (int c2_ = 0; c2_ < 4; ++c2_)           \
                    acc[a_][b_][c2_] = (f32x4){0.f, 0.f, 0.f, 0.f};           \
    }

__global__ __launch_bounds__(256, 2) void k_main(const float* __restrict__ mf,
                                                 const float* __restrict__ HT,
                                                 const _Float16* __restrict__ HTh,
                                                 const _Float16* __restrict__ Ah,
                                                 const _Float16* __restrict__ mhT,
                                                 float* __restrict__ out) {
    __shared__ _Float16 tiles[2][128 * 64];  // A only: 32 KB
    __shared__ _Float16 hbuf[2][N];          // 8 KB
    __shared__ float red[2][4][64];          // 2 KB

    int t = threadIdx.x;
    int jbase = (blockIdx.x >> 5) << 7;
    int f0 = (blockIdx.x & 31) << 1;
    int w = t >> 6, lane = t & 63, q = lane >> 4, l16 = lane & 15;
    int wj = (w & 1) << 6, wk = (w >> 1) << 6;

    // stage H rows once
#pragma unroll
    for (int s = 0; s < 2; ++s) {
        int idx = t + 256 * s;
        ((f16x8*)hbuf)[idx] = *(const f16x8*)&HTh[(size_t)(f0 + (idx >> 8)) * N + (idx & 255) * 8];
    }

    // A staging constants (identical to R2): lane -> (row lane>>3, chunk with XOR)
    int lrow = lane >> 3;
    int lchunk = (lane & 7) ^ lrow;
    size_t aoff = (size_t)(jbase + w * 32 + lrow) * N + lchunk * 8;
    _Float16* la0 = &tiles[0][w * 2048];
    _Float16* la1 = &tiles[1][w * 2048];
    const _Float16* ta0 = &tiles[0][0];
    const _Float16* ta1 = &tiles[1][0];

    float outp[2][4][4];
    f32x4 acc[2][4][4];
#pragma unroll
    for (int a = 0; a < 2; ++a)
#pragma unroll
        for (int b = 0; b < 4; ++b)
#pragma unroll
            for (int c = 0; c < 4; ++c) {
                outp[a][b][c] = 0.f;
                acc[a][b][c] = (f32x4){0.f, 0.f, 0.f, 0.f};
            }

    f16x8 bA[4], bB[4];
    ISSUE_A(0, la0);
    BLOAD(bA, 0, 0);

#pragma unroll 1
    for (int it2 = 0; it2 < NIT; it2 += 2) {
        // ---- first half: compute it2 from tiles[0] ----
        __syncthreads();               // drains glds(it2)->tiles[0] and bA
        ISSUE_A(it2 + 1, la1);
        BLOAD(bB, it2, 1);
        COMPUTE_S(it2, 0, ta0, bA);
        BLOAD(bA, it2 + 1, 0);
        COMPUTE_S(it2, 1, ta0, bB);

        // ---- second half: compute it2+1 from tiles[1] ----
        __syncthreads();               // drains glds(it2+1)->tiles[1] and bA
        ISSUE_A(it2 + 2, la0);
        BLOAD(bB, it2 + 1, 1);
        COMPUTE_S(it2 + 1, 0, ta1, bA);
        BLOAD(bA, it2 + 2, 0);
        COMPUTE_S(it2 + 1, 1, ta1, bB);
        if (((it2 + 1) & 31) == 31) { EPILOGUE((it2 + 1) >> 5); }
    }

    // cross-wave reduce + store
    if (l16 == 0) {
#pragma unroll
        for (int fi = 0; fi < 2; ++fi)
#pragma unroll
            for (int jj = 0; jj < 4; ++jj)
#pragma unroll
                for (int r = 0; r < 4; ++r)
                    red[fi][w][jj * 16 + q * 4 + r] = outp[fi][jj][r];
    }
    __syncthreads();
    if (t < 128) {
        int j = t;
#pragma unroll
        for (int fi = 0; fi < 2; ++fi) {
            float v = (j < 64) ? (red[fi][0][j] + red[fi][2][j])
                               : (red[fi][1][j - 64] + red[fi][3][j - 64]);
            out[(size_t)(jbase + j) * FOUT + f0 + fi] = v;
        }
    }
}

// ---------------- launch ----------------
extern "C" void kernel_launch(void* const* d_in, const int* in_sizes, int n_in,
                              void* d_out, int out_size, void* d_ws, size_t ws_size,
                              hipStream_t stream) {
    const float* X    = (const float*)d_in[0];
    const float* A    = (const float*)d_in[1];
    const float* mf   = (const float*)d_in[2];
    const float* mh   = (const float*)d_in[3];
    const float* W    = (const float*)d_in[4];
    const float* bias = (const float*)d_in[5];
    float* out = (float*)d_out;

    float*    HT  = (float*)d_ws;
    _Float16* HTh = (_Float16*)((char*)d_ws + 524288);
    _Float16* Ah  = (_Float16*)((char*)d_ws + 1048576);
    _Float16* mhT = (_Float16*)((char*)d_ws + 1048576 + 8388608);

    k_h<<<N / 4, 256, 0, stream>>>(X, W, bias, HT, HTh);
    k_a2h<<<(N * N / 4) / 256, 256, 0, stream>>>(A, Ah);
    k_mht<<<(N / 64) * (N / 64), 256, 0, stream>>>(mh, mhT);
    k_main<<<16 * 32, 256, 0, stream>>>(mf, HT, HTh, Ah, mhT, out);
}

// Round 5
// 1389.017 us; speedup vs baseline: 1.0211x; 1.0211x over previous
//
#include <hip/hip_runtime.h>
#include <hip/hip_bf16.h>

// Problem: N=2048, F_IN=128, F_OUT=64
// out[j,f] = sum_{i,k} A[j,i] H[i,f] mh[i,k] H[k,f] mf[j,k],  H = X@W + b
// R5: R2 skeleton (proven), occupancy 2->3 blocks/CU: BI 64->32 (LDS 74->42KB),
// k-range split in 2 halves per (j,f) block (grid 1024), partial-k folded with
// one fp32 atomicAdd per output (2 addends, order-invariant). 3 barrier groups
// per CU drift out of phase -> LDS bursts overlap MFMA bursts across blocks.

typedef __attribute__((ext_vector_type(8))) _Float16 f16x8;
typedef __attribute__((ext_vector_type(4))) _Float16 f16x4;
typedef __attribute__((ext_vector_type(4))) float f32x4;

#define N 2048
#define FOUT 64
#define FIN 128
#define NIT 512   // per block: 8 ktiles * 64 i-steps of 32

__device__ __forceinline__ void gl_lds16(const _Float16* g, _Float16* l) {
    __builtin_amdgcn_global_load_lds(
        (const __attribute__((address_space(1))) void*)g,
        (__attribute__((address_space(3))) void*)l, 16, 0, 0);
}

// ---------------- prep kernels ----------------

__global__ __launch_bounds__(256) void k_h(const float* __restrict__ X,
                                           const float* __restrict__ W,
                                           const float* __restrict__ bias,
                                           float* __restrict__ HT,
                                           _Float16* __restrict__ HTh) {
    __shared__ float Ws[FIN * FOUT];
    __shared__ float Xs[4 * FIN];
    int t = threadIdx.x;
#pragma unroll
    for (int s = 0; s < 32; ++s) Ws[t + 256 * s] = W[t + 256 * s];
    int i0 = blockIdx.x * 4;
#pragma unroll
    for (int s = 0; s < 2; ++s) { int idx = t + 256 * s; Xs[idx] = X[(size_t)i0 * FIN + idx]; }
    __syncthreads();
    int f = t & 63, il = t >> 6;
    float h = bias[f];
#pragma unroll
    for (int p = 0; p < FIN; ++p) h = fmaf(Xs[il * FIN + p], Ws[p * FOUT + f], h);
    int i = i0 + il;
    HT[f * N + i] = h;
    HTh[f * N + i] = (_Float16)h;
}

__global__ __launch_bounds__(256) void k_a2h(const float* __restrict__ A,
                                             _Float16* __restrict__ Ah) {
    int g = blockIdx.x * 256 + threadIdx.x;
    float4 v = ((const float4*)A)[g];
    f16x4 o;
    o[0] = (_Float16)v.x; o[1] = (_Float16)v.y; o[2] = (_Float16)v.z; o[3] = (_Float16)v.w;
    ((f16x4*)Ah)[g] = o;
}

__global__ __launch_bounds__(256) void k_mht(const float* __restrict__ mh,
                                             _Float16* __restrict__ mhT) {
    __shared__ float tile[64][65];
    int t = threadIdx.x;
    int bx = blockIdx.x & 31;
    int by = blockIdx.x >> 5;
#pragma unroll
    for (int s = 0; s < 16; ++s) {
        int lin = t + 256 * s;
        int r = lin >> 6, c = lin & 63;
        tile[r][c] = mh[(size_t)(by * 64 + r) * N + bx * 64 + c];
    }
    __syncthreads();
#pragma unroll
    for (int s = 0; s < 16; ++s) {
        int lin = t + 256 * s;
        int kr = lin >> 6, ic = lin & 63;
        mhT[(size_t)(bx * 64 + kr) * N + by * 64 + ic] = (_Float16)tile[ic][kr];
    }
}

// ---------------- main kernel ----------------
// grid 1024: bid = jtile(4b) | fgroup(5b) | khalf(1b). 256 thr; 128j x 128k x 2f
// per block over k-half [kh*1024, kh*1024+1024). Wave w: wj=(w&1)*64, wk=(w>>1)*64.
// LDS tile row = 32 halves = 4 chunks of 16B; phys_chunk = (log + (row>>1)) & 3.

#define ISSUE(it_, la_, lb_)                                                  \
    {                                                                         \
        int itc_ = ((it_) < NIT) ? (it_) : (NIT - 1);                         \
        int ib_ = (itc_ & 63) << 5;                                           \
        const _Float16* pa_ = Ah + aoff + ib_;                                \
        const _Float16* pb_ = mhT + boff + (size_t)((itc_ >> 6) << 7) * N + ib_; \
        _Pragma("unroll") for (int c_ = 0; c_ < 2; ++c_) {                    \
            gl_lds16(pa_ + c_ * 16 * N, (la_) + c_ * 512);                    \
            gl_lds16(pb_ + c_ * 16 * N, (lb_) + c_ * 512);                    \
        }                                                                     \
    }

#define COMPUTE(it_, ta_, tb_)                                                \
    {                                                                         \
        int ib_ = ((it_) & 63) << 5;                                          \
        f16x8 ar_[4], br_[4];                                                 \
        _Pragma("unroll") for (int x = 0; x < 4; ++x)                         \
            ar_[x] = *(const f16x8*)&(ta_)[(wj + x * 16 + l16) * 32 + pcq];   \
        _Pragma("unroll") for (int x = 0; x < 4; ++x)                         \
            br_[x] = *(const f16x8*)&(tb_)[(wk + x * 16 + l16) * 32 + pcq];   \
        f16x8 h0_ = *(const f16x8*)&hbuf[0][ib_ + (q << 3)];                  \
        f16x8 h1_ = *(const f16x8*)&hbuf[1][ib_ + (q << 3)];                  \
        _Pragma("unroll") for (int jj = 0; jj < 4; ++jj) {                    \
            f16x8 a0_ = ar_[jj] * h0_;                                        \
            f16x8 a1_ = ar_[jj] * h1_;                                        \
            _Pragma("unroll") for (int kk = 0; kk < 4; ++kk) {                \
                acc[0][jj][kk] = __builtin_amdgcn_mfma_f32_16x16x32_f16(      \
                    a0_, br_[kk], acc[0][jj][kk], 0, 0, 0);                   \
                acc[1][jj][kk] = __builtin_amdgcn_mfma_f32_16x16x32_f16(      \
                    a1_, br_[kk], acc[1][jj][kk], 0, 0, 0);                   \
            }                                                                 \
        }                                                                     \
    }

#define EPILOGUE(kt_)                                                         \
    {                                                                         \
        int kbase_ = khbase + ((kt_) << 7);                                   \
        _Pragma("unroll") for (int jj = 0; jj < 4; ++jj) {                    \
            float t0_[4] = {0.f, 0.f, 0.f, 0.f};                              \
            float t1_[4] = {0.f, 0.f, 0.f, 0.f};                              \
            _Pragma("unroll") for (int kk = 0; kk < 4; ++kk) {                \
                int kg_ = kbase_ + wk + kk * 16 + l16;                        \
                float hk0_ = HT[f0 * N + kg_];                                \
                float hk1_ = HT[(f0 + 1) * N + kg_];                          \
                int jrow_ = jbase + wj + jj * 16 + q * 4;                     \
                _Pragma("unroll") for (int r = 0; r < 4; ++r) {               \
                    float m_ = mf[(size_t)(jrow_ + r) * N + kg_];             \
                    t0_[r] = fmaf(acc[0][jj][kk][r], m_ * hk0_, t0_[r]);      \
                    t1_[r] = fmaf(acc[1][jj][kk][r], m_ * hk1_, t1_[r]);      \
                }                                                             \
            }                                                                 \
            _Pragma("unroll") for (int r = 0; r < 4; ++r) {                   \
                float v0_ = t0_[r], v1_ = t1_[r];                             \
                v0_ += __shfl_xor(v0_, 1); v1_ += __shfl_xor(v1_, 1);         \
                v0_ += __shfl_xor(v0_, 2); v1_ += __shfl_xor(v1_, 2);         \
                v0_ += __shfl_xor(v0_, 4); v1_ += __shfl_xor(v1_, 4);         \
                v0_ += __shfl_xor(v0_, 8); v1_ += __shfl_xor(v1_, 8);         \
                outp[0][jj][r] += v0_;                                        \
                outp[1][jj][r] += v1_;                                        \
            }                                                                 \
        }                                                                     \
        _Pragma("unroll") for (int a_ = 0; a_ < 2; ++a_)                      \
            _Pragma("unroll") for (int b_ = 0; b_ < 4; ++b_)                  \
                _Pragma("unroll") for (int c2_ = 0; c2_ < 4; ++c2_)           \
                    acc[a_][b_][c2_] = (f32x4){0.f, 0.f, 0.f, 0.f};           \
    }

__global__ __launch_bounds__(256, 3) void k_main(const float* __restrict__ mf,
                                                 const float* __restrict__ HT,
                                                 const _Float16* __restrict__ HTh,
                                                 const _Float16* __restrict__ Ah,
                                                 const _Float16* __restrict__ mhT,
                                                 float* __restrict__ out) {
    __shared__ _Float16 tiles[2][2][128 * 32];  // [buf][op] 32 KB
    __shared__ _Float16 hbuf[2][N];             // 8 KB
    __shared__ float red[2][4][64];             // 2 KB

    int t = threadIdx.x;
    int bid = blockIdx.x;
    int kh = bid & 1;
    int f0 = ((bid >> 1) & 31) << 1;
    int jbase = (bid >> 6) << 7;
    int khbase = kh << 10;
    int w = t >> 6, lane = t & 63, q = lane >> 4, l16 = lane & 15;
    int wj = (w & 1) << 6, wk = (w >> 1) << 6;

    // stage H rows once
#pragma unroll
    for (int s = 0; s < 2; ++s) {
        int idx = t + 256 * s;
        ((f16x8*)hbuf)[idx] = *(const f16x8*)&HTh[(size_t)(f0 + (idx >> 8)) * N + (idx & 255) * 8];
    }

    // staging constants: glds lane l -> lds byte l*16 => row_local=l>>2, phys chunk=l&3
    int lrow = lane >> 2;                            // 0..15
    int lc = ((lane & 3) - (lrow >> 1)) & 3;         // logical chunk to fetch
    size_t aoff = (size_t)(jbase + w * 32 + lrow) * N + lc * 8;
    size_t boff = (size_t)(khbase + w * 32 + lrow) * N + lc * 8;
    _Float16* la0 = &tiles[0][0][w * 1024];
    _Float16* lb0 = &tiles[0][1][w * 1024];
    _Float16* la1 = &tiles[1][0][w * 1024];
    _Float16* lb1 = &tiles[1][1][w * 1024];
    const _Float16* ta0 = &tiles[0][0][0];
    const _Float16* tb0 = &tiles[0][1][0];
    const _Float16* ta1 = &tiles[1][0][0];
    const _Float16* tb1 = &tiles[1][1][0];

    // fragment-read swizzled chunk offset (halves): phys = (q + (l16>>1)) & 3
    int pcq = ((q + (l16 >> 1)) & 3) << 3;

    float outp[2][4][4];
    f32x4 acc[2][4][4];
#pragma unroll
    for (int a = 0; a < 2; ++a)
#pragma unroll
        for (int b = 0; b < 4; ++b)
#pragma unroll
            for (int c = 0; c < 4; ++c) {
                outp[a][b][c] = 0.f;
                acc[a][b][c] = (f32x4){0.f, 0.f, 0.f, 0.f};
            }

    ISSUE(0, la0, lb0);

#pragma unroll 1
    for (int it2 = 0; it2 < NIT; it2 += 2) {
        __syncthreads();                 // drains glds(it2)->tiles[0]
        ISSUE(it2 + 1, la1, lb1);
        COMPUTE(it2, ta0, tb0);

        __syncthreads();                 // drains glds(it2+1)->tiles[1]
        ISSUE(it2 + 2, la0, lb0);
        COMPUTE(it2 + 1, ta1, tb1);
        if (((it2 + 1) & 63) == 63) { EPILOGUE((it2 + 1) >> 6); }
    }

    // cross-wave reduce + atomic store (2 k-half blocks per output)
    if (l16 == 0) {
#pragma unroll
        for (int fi = 0; fi < 2; ++fi)
#pragma unroll
            for (int jj = 0; jj < 4; ++jj)
#pragma unroll
                for (int r = 0; r < 4; ++r)
                    red[fi][w][jj * 16 + q * 4 + r] = outp[fi][jj][r];
    }
    __syncthreads();
    if (t < 128) {
        int j = t;
#pragma unroll
        for (int fi = 0; fi < 2; ++fi) {
            float v = (j < 64) ? (red[fi][0][j] + red[fi][2][j])
                               : (red[fi][1][j - 64] + red[fi][3][j - 64]);
            atomicAdd(&out[(size_t)(jbase + j) * FOUT + f0 + fi], v);
        }
    }
}

// ---------------- launch ----------------
extern "C" void kernel_launch(void* const* d_in, const int* in_sizes, int n_in,
                              void* d_out, int out_size, void* d_ws, size_t ws_size,
                              hipStream_t stream) {
    const float* X    = (const float*)d_in[0];
    const float* A    = (const float*)d_in[1];
    const float* mf   = (const float*)d_in[2];
    const float* mh   = (const float*)d_in[3];
    const float* W    = (const float*)d_in[4];
    const float* bias = (const float*)d_in[5];
    float* out = (float*)d_out;

    float*    HT  = (float*)d_ws;
    _Float16* HTh = (_Float16*)((char*)d_ws + 524288);
    _Float16* Ah  = (_Float16*)((char*)d_ws + 1048576);
    _Float16* mhT = (_Float16*)((char*)d_ws + 1048576 + 8388608);

    hipMemsetAsync(out, 0, (size_t)N * FOUT * sizeof(float), stream);
    k_h<<<N / 4, 256, 0, stream>>>(X, W, bias, HT, HTh);
    k_a2h<<<(N * N / 4) / 256, 256, 0, stream>>>(A, Ah);
    k_mht<<<(N / 64) * (N / 64), 256, 0, stream>>>(mh, mhT);
    k_main<<<16 * 32 * 2, 256, 0, stream>>>(mf, HT, HTh, Ah, mhT, out);
}

// Round 6
// 1062.186 us; speedup vs baseline: 1.3353x; 1.3077x over previous
//
#include <hip/hip_runtime.h>
#include <hip/hip_bf16.h>

// Problem: N=2048, F_IN=128, F_OUT=64
// out[j,f] = sum_{i,k} A[j,i] H[i,f] mh[i,k] H[k,f] mf[j,k],  H = X@W + b
// R6: R2 skeleton (990us anchor: 128x64 tiles, 2 blocks/CU, glds staging)
// with the __syncthreads() drain replaced by raw s_barrier + s_waitcnt
// vmcnt(8): prefetched global_load_lds stay in flight ACROSS the barrier
// (hipBLASLt's "vmcnt never 0" pattern). 2 bare barriers/it, no full drain.

typedef __attribute__((ext_vector_type(8))) _Float16 f16x8;
typedef __attribute__((ext_vector_type(4))) _Float16 f16x4;
typedef __attribute__((ext_vector_type(4))) float f32x4;

#define N 2048
#define FOUT 64
#define FIN 128
#define NIT 512   // 16 ktiles * 32 its of 64-i

__device__ __forceinline__ void gl_lds16(const _Float16* g, _Float16* l) {
    __builtin_amdgcn_global_load_lds(
        (const __attribute__((address_space(1))) void*)g,
        (__attribute__((address_space(3))) void*)l, 16, 0, 0);
}

// ---------------- prep kernels ----------------

__global__ __launch_bounds__(256) void k_h(const float* __restrict__ X,
                                           const float* __restrict__ W,
                                           const float* __restrict__ bias,
                                           float* __restrict__ HT,
                                           _Float16* __restrict__ HTh) {
    __shared__ float Ws[FIN * FOUT];
    __shared__ float Xs[4 * FIN];
    int t = threadIdx.x;
#pragma unroll
    for (int s = 0; s < 32; ++s) Ws[t + 256 * s] = W[t + 256 * s];
    int i0 = blockIdx.x * 4;
#pragma unroll
    for (int s = 0; s < 2; ++s) { int idx = t + 256 * s; Xs[idx] = X[(size_t)i0 * FIN + idx]; }
    __syncthreads();
    int f = t & 63, il = t >> 6;
    float h = bias[f];
#pragma unroll
    for (int p = 0; p < FIN; ++p) h = fmaf(Xs[il * FIN + p], Ws[p * FOUT + f], h);
    int i = i0 + il;
    HT[f * N + i] = h;
    HTh[f * N + i] = (_Float16)h;
}

__global__ __launch_bounds__(256) void k_a2h(const float* __restrict__ A,
                                             _Float16* __restrict__ Ah) {
    int g = blockIdx.x * 256 + threadIdx.x;
    float4 v = ((const float4*)A)[g];
    f16x4 o;
    o[0] = (_Float16)v.x; o[1] = (_Float16)v.y; o[2] = (_Float16)v.z; o[3] = (_Float16)v.w;
    ((f16x4*)Ah)[g] = o;
}

__global__ __launch_bounds__(256) void k_mht(const float* __restrict__ mh,
                                             _Float16* __restrict__ mhT) {
    __shared__ float tile[64][65];
    int t = threadIdx.x;
    int bx = blockIdx.x & 31;
    int by = blockIdx.x >> 5;
#pragma unroll
    for (int s = 0; s < 16; ++s) {
        int lin = t + 256 * s;
        int r = lin >> 6, c = lin & 63;
        tile[r][c] = mh[(size_t)(by * 64 + r) * N + bx * 64 + c];
    }
    __syncthreads();
#pragma unroll
    for (int s = 0; s < 16; ++s) {
        int lin = t + 256 * s;
        int kr = lin >> 6, ic = lin & 63;
        mhT[(size_t)(bx * 64 + kr) * N + by * 64 + ic] = (_Float16)tile[ic][kr];
    }
}

// ---------------- main kernel ----------------
// grid 512 = 16 jtiles * 32 fgroups; 256 threads; block = 128j x 128k x 2f.
// Wave w: wj=(w&1)*64, wk=(w>>1)*64. LDS tile row = 64 halves = 8 chunks of
// 16B; phys_chunk = log_chunk ^ (row&7).

#define ISSUE(it_, la_, lb_)                                                  \
    {                                                                         \
        int itc_ = ((it_) < NIT) ? (it_) : (NIT - 1);                         \
        int ib_ = (itc_ & 31) << 6;                                           \
        const _Float16* pa_ = Ah + aoff + ib_;                                \
        const _Float16* pb_ = mhT + boff + (size_t)((itc_ >> 5) << 7) * N + ib_; \
        _Pragma("unroll") for (int c_ = 0; c_ < 4; ++c_) {                    \
            gl_lds16(pa_ + c_ * 8 * N, (la_) + c_ * 512);                     \
            gl_lds16(pb_ + c_ * 8 * N, (lb_) + c_ * 512);                     \
        }                                                                     \
    }

#define COMPUTE(it_, ta_, tb_)                                                \
    {                                                                         \
        int ibb_ = ((it_) & 31) << 6;                                         \
        _Pragma("unroll") for (int s = 0; s < 2; ++s) {                       \
            f16x8 ar_[4], br_[4];                                             \
            _Pragma("unroll") for (int x = 0; x < 4; ++x)                     \
                ar_[x] = *(const f16x8*)&(ta_)[(wj + x * 16 + l16) * 64 +     \
                                               (((q + 4 * s) ^ (l16 & 7)) << 3)]; \
            _Pragma("unroll") for (int x = 0; x < 4; ++x)                     \
                br_[x] = *(const f16x8*)&(tb_)[(wk + x * 16 + l16) * 64 +     \
                                               (((q + 4 * s) ^ (l16 & 7)) << 3)]; \
            f16x8 h0_ = *(const f16x8*)&hbuf[0][ibb_ + s * 32 + (q << 3)];    \
            f16x8 h1_ = *(const f16x8*)&hbuf[1][ibb_ + s * 32 + (q << 3)];    \
            _Pragma("unroll") for (int jj = 0; jj < 4; ++jj) {                \
                f16x8 a0_ = ar_[jj] * h0_;                                    \
                f16x8 a1_ = ar_[jj] * h1_;                                    \
                _Pragma("unroll") for (int kk = 0; kk < 4; ++kk) {            \
                    acc[0][jj][kk] = __builtin_amdgcn_mfma_f32_16x16x32_f16(  \
                        a0_, br_[kk], acc[0][jj][kk], 0, 0, 0);               \
                    acc[1][jj][kk] = __builtin_amdgcn_mfma_f32_16x16x32_f16(  \
                        a1_, br_[kk], acc[1][jj][kk], 0, 0, 0);               \
                }                                                             \
            }                                                                 \
        }                                                                     \
    }

#define EPILOGUE(kt_)                                                         \
    {                                                                         \
        int kbase_ = (kt_) << 7;                                              \
        _Pragma("unroll") for (int jj = 0; jj < 4; ++jj) {                    \
            float t0_[4] = {0.f, 0.f, 0.f, 0.f};                              \
            float t1_[4] = {0.f, 0.f, 0.f, 0.f};                              \
            _Pragma("unroll") for (int kk = 0; kk < 4; ++kk) {                \
                int kg_ = kbase_ + wk + kk * 16 + l16;                        \
                float hk0_ = HT[f0 * N + kg_];                                \
                float hk1_ = HT[(f0 + 1) * N + kg_];                          \
                int jrow_ = jbase + wj + jj * 16 + q * 4;                     \
                _Pragma("unroll") for (int r = 0; r < 4; ++r) {               \
                    float m_ = mf[(size_t)(jrow_ + r) * N + kg_];             \
                    t0_[r] = fmaf(acc[0][jj][kk][r], m_ * hk0_, t0_[r]);      \
                    t1_[r] = fmaf(acc[1][jj][kk][r], m_ * hk1_, t1_[r]);      \
                }                                                             \
            }                                                                 \
            _Pragma("unroll") for (int r = 0; r < 4; ++r) {                   \
                float v0_ = t0_[r], v1_ = t1_[r];                             \
                v0_ += __shfl_xor(v0_, 1); v1_ += __shfl_xor(v1_, 1);         \
                v0_ += __shfl_xor(v0_, 2); v1_ += __shfl_xor(v1_, 2);         \
                v0_ += __shfl_xor(v0_, 4); v1_ += __shfl_xor(v1_, 4);         \
                v0_ += __shfl_xor(v0_, 8); v1_ += __shfl_xor(v1_, 8);         \
                outp[0][jj][r] += v0_;                                        \
                outp[1][jj][r] += v1_;                                        \
            }                                                                 \
        }                                                                     \
        _Pragma("unroll") for (int a_ = 0; a_ < 2; ++a_)                      \
            _Pragma("unroll") for (int b_ = 0; b_ < 4; ++b_)                  \
                _Pragma("unroll") for (int c2_ = 0; c2_ < 4; ++c2_)           \
                    acc[a_][b_][c2_] = (f32x4){0.f, 0.f, 0.f, 0.f};           \
    }

// partial waitcnt + bare barrier (no vmcnt(0) drain), order pinned
#define SYNC_VM8()                                                            \
    __builtin_amdgcn_sched_barrier(0);                                        \
    __builtin_amdgcn_s_waitcnt(0x0F78); /* vmcnt<=8, lgkm/exp free */         \
    __builtin_amdgcn_s_barrier();                                             \
    __builtin_amdgcn_sched_barrier(0);

#define SYNC_BARE()                                                           \
    __builtin_amdgcn_sched_barrier(0);                                        \
    __builtin_amdgcn_s_barrier();                                             \
    __builtin_amdgcn_sched_barrier(0);

__global__ __launch_bounds__(256, 2) void k_main(const float* __restrict__ mf,
                                                 const float* __restrict__ HT,
                                                 const _Float16* __restrict__ HTh,
                                                 const _Float16* __restrict__ Ah,
                                                 const _Float16* __restrict__ mhT,
                                                 float* __restrict__ out) {
    __shared__ _Float16 tiles[2][2][128 * 64];  // [buf][op] 64 KB
    __shared__ _Float16 hbuf[2][N];             // 8 KB
    __shared__ float red[2][4][64];             // 2 KB

    int t = threadIdx.x;
    int jbase = (blockIdx.x >> 5) << 7;
    int f0 = (blockIdx.x & 31) << 1;
    int w = t >> 6, lane = t & 63, q = lane >> 4, l16 = lane & 15;
    int wj = (w & 1) << 6, wk = (w >> 1) << 6;

    // stage H rows once (real __syncthreads: full drain, happens once)
#pragma unroll
    for (int s = 0; s < 2; ++s) {
        int idx = t + 256 * s;
        ((f16x8*)hbuf)[idx] = *(const f16x8*)&HTh[(size_t)(f0 + (idx >> 8)) * N + (idx & 255) * 8];
    }
    __syncthreads();

    // staging constants: glds lane l -> lds byte l*16; row=l>>3, phys chunk=l&7
    int lrow = lane >> 3;
    int lchunk = (lane & 7) ^ lrow;   // global chunk fetched into phys l&7
    size_t aoff = (size_t)(jbase + w * 32 + lrow) * N + lchunk * 8;
    size_t boff = (size_t)(w * 32 + lrow) * N + lchunk * 8;
    _Float16* la0 = &tiles[0][0][w * 2048];
    _Float16* lb0 = &tiles[0][1][w * 2048];
    _Float16* la1 = &tiles[1][0][w * 2048];
    _Float16* lb1 = &tiles[1][1][w * 2048];
    const _Float16* ta0 = &tiles[0][0][0];
    const _Float16* tb0 = &tiles[0][1][0];
    const _Float16* ta1 = &tiles[1][0][0];
    const _Float16* tb1 = &tiles[1][1][0];

    float outp[2][4][4];
    f32x4 acc[2][4][4];
#pragma unroll
    for (int a = 0; a < 2; ++a)
#pragma unroll
        for (int b = 0; b < 4; ++b)
#pragma unroll
            for (int c = 0; c < 4; ++c) {
                outp[a][b][c] = 0.f;
                acc[a][b][c] = (f32x4){0.f, 0.f, 0.f, 0.f};
            }

    ISSUE(0, la0, lb0);
    ISSUE(1, la1, lb1);

#pragma unroll 1
    for (int it2 = 0; it2 < NIT; it2 += 2) {
        // ---- even: wait own glds(it2) [glds(it2+1) stays in flight] ----
        SYNC_VM8();
        COMPUTE(it2, ta0, tb0);
        SYNC_BARE();                       // everyone done reading buf0
        ISSUE(it2 + 2, la0, lb0);

        // ---- odd ----
        SYNC_VM8();
        COMPUTE(it2 + 1, ta1, tb1);
        SYNC_BARE();                       // everyone done reading buf1
        ISSUE(it2 + 3, la1, lb1);
        if (((it2 + 1) & 31) == 31) { EPILOGUE((it2 + 1) >> 5); }
    }

    // cross-wave reduce + store
    __syncthreads();
    if (l16 == 0) {
#pragma unroll
        for (int fi = 0; fi < 2; ++fi)
#pragma unroll
            for (int jj = 0; jj < 4; ++jj)
#pragma unroll
                for (int r = 0; r < 4; ++r)
                    red[fi][w][jj * 16 + q * 4 + r] = outp[fi][jj][r];
    }
    __syncthreads();
    if (t < 128) {
        int j = t;
#pragma unroll
        for (int fi = 0; fi < 2; ++fi) {
            float v = (j < 64) ? (red[fi][0][j] + red[fi][2][j])
                               : (red[fi][1][j - 64] + red[fi][3][j - 64]);
            out[(size_t)(jbase + j) * FOUT + f0 + fi] = v;
        }
    }
}

// ---------------- launch ----------------
extern "C" void kernel_launch(void* const* d_in, const int* in_sizes, int n_in,
                              void* d_out, int out_size, void* d_ws, size_t ws_size,
                              hipStream_t stream) {
    const float* X    = (const float*)d_in[0];
    const float* A    = (const float*)d_in[1];
    const float* mf   = (const float*)d_in[2];
    const float* mh   = (const float*)d_in[3];
    const float* W    = (const float*)d_in[4];
    const float* bias = (const float*)d_in[5];
    float* out = (float*)d_out;

    float*    HT  = (float*)d_ws;
    _Float16* HTh = (_Float16*)((char*)d_ws + 524288);
    _Float16* Ah  = (_Float16*)((char*)d_ws + 1048576);
    _Float16* mhT = (_Float16*)((char*)d_ws + 1048576 + 8388608);

    k_h<<<N / 4, 256, 0, stream>>>(X, W, bias, HT, HTh);
    k_a2h<<<(N * N / 4) / 256, 256, 0, stream>>>(A, Ah);
    k_mht<<<(N / 64) * (N / 64), 256, 0, stream>>>(mh, mhT);
    k_main<<<16 * 32, 256, 0, stream>>>(mf, HT, HTh, Ah, mhT, out);
}

// Round 7
// 1042.414 us; speedup vs baseline: 1.3606x; 1.0190x over previous
//
#include <hip/hip_runtime.h>
#include <hip/hip_bf16.h>

// Problem: N=2048, F_IN=128, F_OUT=64
// out[j,f] = sum_{i,k} A[j,i] H[i,f] mh[i,k] H[k,f] mf[j,k],  H = X@W + b
// R7: R2 skeleton (990us anchor) + intra-phase LDS/MFMA interleave via
// sched_group_barrier (DS10|MFMA16|DS5|MFMA8|DS5|MFMA40) and outp partials
// moved to LDS (frees 32 VGPRs for the wider fragment-liveness window).

typedef __attribute__((ext_vector_type(8))) _Float16 f16x8;
typedef __attribute__((ext_vector_type(4))) _Float16 f16x4;
typedef __attribute__((ext_vector_type(4))) float f32x4;

#define N 2048
#define FOUT 64
#define FIN 128
#define NIT 512   // 16 ktiles * 32 its of 64-i

__device__ __forceinline__ void gl_lds16(const _Float16* g, _Float16* l) {
    __builtin_amdgcn_global_load_lds(
        (const __attribute__((address_space(1))) void*)g,
        (__attribute__((address_space(3))) void*)l, 16, 0, 0);
}

// ---------------- prep kernels ----------------

__global__ __launch_bounds__(256) void k_h(const float* __restrict__ X,
                                           const float* __restrict__ W,
                                           const float* __restrict__ bias,
                                           float* __restrict__ HT,
                                           _Float16* __restrict__ HTh) {
    __shared__ float Ws[FIN * FOUT];
    __shared__ float Xs[4 * FIN];
    int t = threadIdx.x;
#pragma unroll
    for (int s = 0; s < 32; ++s) Ws[t + 256 * s] = W[t + 256 * s];
    int i0 = blockIdx.x * 4;
#pragma unroll
    for (int s = 0; s < 2; ++s) { int idx = t + 256 * s; Xs[idx] = X[(size_t)i0 * FIN + idx]; }
    __syncthreads();
    int f = t & 63, il = t >> 6;
    float h = bias[f];
#pragma unroll
    for (int p = 0; p < FIN; ++p) h = fmaf(Xs[il * FIN + p], Ws[p * FOUT + f], h);
    int i = i0 + il;
    HT[f * N + i] = h;
    HTh[f * N + i] = (_Float16)h;
}

__global__ __launch_bounds__(256) void k_a2h(const float* __restrict__ A,
                                             _Float16* __restrict__ Ah) {
    int g = blockIdx.x * 256 + threadIdx.x;
    float4 v = ((const float4*)A)[g];
    f16x4 o;
    o[0] = (_Float16)v.x; o[1] = (_Float16)v.y; o[2] = (_Float16)v.z; o[3] = (_Float16)v.w;
    ((f16x4*)Ah)[g] = o;
}

__global__ __launch_bounds__(256) void k_mht(const float* __restrict__ mh,
                                             _Float16* __restrict__ mhT) {
    __shared__ float tile[64][65];
    int t = threadIdx.x;
    int bx = blockIdx.x & 31;
    int by = blockIdx.x >> 5;
#pragma unroll
    for (int s = 0; s < 16; ++s) {
        int lin = t + 256 * s;
        int r = lin >> 6, c = lin & 63;
        tile[r][c] = mh[(size_t)(by * 64 + r) * N + bx * 64 + c];
    }
    __syncthreads();
#pragma unroll
    for (int s = 0; s < 16; ++s) {
        int lin = t + 256 * s;
        int kr = lin >> 6, ic = lin & 63;
        mhT[(size_t)(bx * 64 + kr) * N + by * 64 + ic] = (_Float16)tile[ic][kr];
    }
}

// ---------------- main kernel ----------------
// grid 512 = 16 jtiles * 32 fgroups; 256 threads; block = 128j x 128k x 2f.
// Wave w: wj=(w&1)*64, wk=(w>>1)*64. LDS tile row = 64 halves = 8 chunks of
// 16B; phys_chunk = log_chunk ^ (row&7).

#define ISSUE(it_, la_, lb_)                                                  \
    {                                                                         \
        int itc_ = ((it_) < NIT) ? (it_) : (NIT - 1);                         \
        int ib_ = (itc_ & 31) << 6;                                           \
        const _Float16* pa_ = Ah + aoff + ib_;                                \
        const _Float16* pb_ = mhT + boff + (size_t)((itc_ >> 5) << 7) * N + ib_; \
        _Pragma("unroll") for (int c_ = 0; c_ < 4; ++c_) {                    \
            gl_lds16(pa_ + c_ * 8 * N, (la_) + c_ * 512);                     \
            gl_lds16(pb_ + c_ * 8 * N, (lb_) + c_ * 512);                     \
        }                                                                     \
    }

// one 64-i iteration: 20 ds_reads + 64 MFMA, scheduling template pinned so
// MFMAs start after the first 10 reads and s1 reads hide under s0 MFMAs.
#define COMPUTE(it_, ta_, tb_)                                                \
    {                                                                         \
        int ibb_ = ((it_) & 31) << 6;                                         \
        f16x8 h00_ = *(const f16x8*)&hbuf[0][ibb_ + (q << 3)];                \
        f16x8 h01_ = *(const f16x8*)&hbuf[1][ibb_ + (q << 3)];                \
        f16x8 ar0_[4], br0_[4];                                               \
        _Pragma("unroll") for (int x = 0; x < 4; ++x) {                       \
            ar0_[x] = *(const f16x8*)&(ta_)[(wj + x * 16 + l16) * 64 +        \
                                            ((q ^ (l16 & 7)) << 3)];          \
            br0_[x] = *(const f16x8*)&(tb_)[(wk + x * 16 + l16) * 64 +        \
                                            ((q ^ (l16 & 7)) << 3)];          \
        }                                                                     \
        f16x8 h10_ = *(const f16x8*)&hbuf[0][ibb_ + 32 + (q << 3)];           \
        f16x8 h11_ = *(const f16x8*)&hbuf[1][ibb_ + 32 + (q << 3)];           \
        f16x8 ar1_[4], br1_[4];                                               \
        _Pragma("unroll") for (int x = 0; x < 4; ++x) {                       \
            ar1_[x] = *(const f16x8*)&(ta_)[(wj + x * 16 + l16) * 64 +        \
                                            (((q + 4) ^ (l16 & 7)) << 3)];    \
            br1_[x] = *(const f16x8*)&(tb_)[(wk + x * 16 + l16) * 64 +        \
                                            (((q + 4) ^ (l16 & 7)) << 3)];    \
        }                                                                     \
        _Pragma("unroll") for (int jj = 0; jj < 4; ++jj) {                    \
            f16x8 a00_ = ar0_[jj] * h00_;                                     \
            f16x8 a01_ = ar0_[jj] * h01_;                                     \
            _Pragma("unroll") for (int kk = 0; kk < 4; ++kk) {                \
                acc[0][jj][kk] = __builtin_amdgcn_mfma_f32_16x16x32_f16(      \
                    a00_, br0_[kk], acc[0][jj][kk], 0, 0, 0);                 \
                acc[1][jj][kk] = __builtin_amdgcn_mfma_f32_16x16x32_f16(      \
                    a01_, br0_[kk], acc[1][jj][kk], 0, 0, 0);                 \
            }                                                                 \
        }                                                                     \
        _Pragma("unroll") for (int jj = 0; jj < 4; ++jj) {                    \
            f16x8 a10_ = ar1_[jj] * h10_;                                     \
            f16x8 a11_ = ar1_[jj] * h11_;                                     \
            _Pragma("unroll") for (int kk = 0; kk < 4; ++kk) {                \
                acc[0][jj][kk] = __builtin_amdgcn_mfma_f32_16x16x32_f16(      \
                    a10_, br1_[kk], acc[0][jj][kk], 0, 0, 0);                 \
                acc[1][jj][kk] = __builtin_amdgcn_mfma_f32_16x16x32_f16(      \
                    a11_, br1_[kk], acc[1][jj][kk], 0, 0, 0);                 \
            }                                                                 \
        }                                                                     \
        __builtin_amdgcn_sched_group_barrier(0x100, 10, 0); /* DS  x10 */     \
        __builtin_amdgcn_sched_group_barrier(0x008, 16, 0); /* MFMA x16 */    \
        __builtin_amdgcn_sched_group_barrier(0x100,  5, 0); /* DS  x5  */     \
        __builtin_amdgcn_sched_group_barrier(0x008,  8, 0); /* MFMA x8  */    \
        __builtin_amdgcn_sched_group_barrier(0x100,  5, 0); /* DS  x5  */     \
        __builtin_amdgcn_sched_group_barrier(0x008, 40, 0); /* MFMA x40 */    \
    }

// fold k-tile into LDS-resident partials (red[] accumulates across ktiles)
#define EPILOGUE(kt_)                                                         \
    {                                                                         \
        int kbase_ = (kt_) << 7;                                              \
        _Pragma("unroll") for (int jj = 0; jj < 4; ++jj) {                    \
            float t0_[4] = {0.f, 0.f, 0.f, 0.f};                              \
            float t1_[4] = {0.f, 0.f, 0.f, 0.f};                              \
            _Pragma("unroll") for (int kk = 0; kk < 4; ++kk) {                \
                int kg_ = kbase_ + wk + kk * 16 + l16;                        \
                float hk0_ = HT[f0 * N + kg_];                                \
                float hk1_ = HT[(f0 + 1) * N + kg_];                          \
                int jrow_ = jbase + wj + jj * 16 + q * 4;                     \
                _Pragma("unroll") for (int r = 0; r < 4; ++r) {               \
                    float m_ = mf[(size_t)(jrow_ + r) * N + kg_];             \
                    t0_[r] = fmaf(acc[0][jj][kk][r], m_ * hk0_, t0_[r]);      \
                    t1_[r] = fmaf(acc[1][jj][kk][r], m_ * hk1_, t1_[r]);      \
                }                                                             \
            }                                                                 \
            _Pragma("unroll") for (int r = 0; r < 4; ++r) {                   \
                float v0_ = t0_[r], v1_ = t1_[r];                             \
                v0_ += __shfl_xor(v0_, 1); v1_ += __shfl_xor(v1_, 1);         \
                v0_ += __shfl_xor(v0_, 2); v1_ += __shfl_xor(v1_, 2);         \
                v0_ += __shfl_xor(v0_, 4); v1_ += __shfl_xor(v1_, 4);         \
                v0_ += __shfl_xor(v0_, 8); v1_ += __shfl_xor(v1_, 8);         \
                if (l16 == 0) {                                               \
                    red[0][w][jj * 16 + (q << 2) + r] += v0_;                 \
                    red[1][w][jj * 16 + (q << 2) + r] += v1_;                 \
                }                                                             \
            }                                                                 \
        }                                                                     \
        _Pragma("unroll") for (int a_ = 0; a_ < 2; ++a_)                      \
            _Pragma("unroll") for (int b_ = 0; b_ < 4; ++b_)                  \
                _Pragma("unroll") for (int c2_ = 0; c2_ < 4; ++c2_)           \
                    acc[a_][b_][c2_] = (f32x4){0.f, 0.f, 0.f, 0.f};           \
    }

__global__ __launch_bounds__(256, 2) void k_main(const float* __restrict__ mf,
                                                 const float* __restrict__ HT,
                                                 const _Float16* __restrict__ HTh,
                                                 const _Float16* __restrict__ Ah,
                                                 const _Float16* __restrict__ mhT,
                                                 float* __restrict__ out) {
    __shared__ _Float16 tiles[2][2][128 * 64];  // [buf][op] 64 KB
    __shared__ _Float16 hbuf[2][N];             // 8 KB
    __shared__ float red[2][4][64];             // 2 KB, accumulates partials

    int t = threadIdx.x;
    int jbase = (blockIdx.x >> 5) << 7;
    int f0 = (blockIdx.x & 31) << 1;
    int w = t >> 6, lane = t & 63, q = lane >> 4, l16 = lane & 15;
    int wj = (w & 1) << 6, wk = (w >> 1) << 6;

    // stage H rows + zero red, once
#pragma unroll
    for (int s = 0; s < 2; ++s) {
        int idx = t + 256 * s;
        ((f16x8*)hbuf)[idx] = *(const f16x8*)&HTh[(size_t)(f0 + (idx >> 8)) * N + (idx & 255) * 8];
        ((float*)red)[idx] = 0.f;
    }
    __syncthreads();

    // staging constants: glds lane l -> lds byte l*16; row=l>>3, phys chunk=l&7
    int lrow = lane >> 3;
    int lchunk = (lane & 7) ^ lrow;
    size_t aoff = (size_t)(jbase + w * 32 + lrow) * N + lchunk * 8;
    size_t boff = (size_t)(w * 32 + lrow) * N + lchunk * 8;
    _Float16* la0 = &tiles[0][0][w * 2048];
    _Float16* lb0 = &tiles[0][1][w * 2048];
    _Float16* la1 = &tiles[1][0][w * 2048];
    _Float16* lb1 = &tiles[1][1][w * 2048];
    const _Float16* ta0 = &tiles[0][0][0];
    const _Float16* tb0 = &tiles[0][1][0];
    const _Float16* ta1 = &tiles[1][0][0];
    const _Float16* tb1 = &tiles[1][1][0];

    f32x4 acc[2][4][4];
#pragma unroll
    for (int a = 0; a < 2; ++a)
#pragma unroll
        for (int b = 0; b < 4; ++b)
#pragma unroll
            for (int c = 0; c < 4; ++c) acc[a][b][c] = (f32x4){0.f, 0.f, 0.f, 0.f};

    ISSUE(0, la0, lb0);

#pragma unroll 1
    for (int it2 = 0; it2 < NIT; it2 += 2) {
        __syncthreads();                 // drains glds(it2)->tiles[0]
        ISSUE(it2 + 1, la1, lb1);
        COMPUTE(it2, ta0, tb0);

        __syncthreads();                 // drains glds(it2+1)->tiles[1]
        ISSUE(it2 + 2, la0, lb0);
        COMPUTE(it2 + 1, ta1, tb1);
        if (((it2 + 1) & 31) == 31) { EPILOGUE((it2 + 1) >> 5); }
    }

    // cross-wave reduce + store (red already holds per-wave sums)
    __syncthreads();
    if (t < 128) {
        int j = t;
#pragma unroll
        for (int fi = 0; fi < 2; ++fi) {
            float v = (j < 64) ? (red[fi][0][j] + red[fi][2][j])
                               : (red[fi][1][j - 64] + red[fi][3][j - 64]);
            out[(size_t)(jbase + j) * FOUT + f0 + fi] = v;
        }
    }
}

// ---------------- launch ----------------
extern "C" void kernel_launch(void* const* d_in, const int* in_sizes, int n_in,
                              void* d_out, int out_size, void* d_ws, size_t ws_size,
                              hipStream_t stream) {
    const float* X    = (const float*)d_in[0];
    const float* A    = (const float*)d_in[1];
    const float* mf   = (const float*)d_in[2];
    const float* mh   = (const float*)d_in[3];
    const float* W    = (const float*)d_in[4];
    const float* bias = (const float*)d_in[5];
    float* out = (float*)d_out;

    float*    HT  = (float*)d_ws;
    _Float16* HTh = (_Float16*)((char*)d_ws + 524288);
    _Float16* Ah  = (_Float16*)((char*)d_ws + 1048576);
    _Float16* mhT = (_Float16*)((char*)d_ws + 1048576 + 8388608);

    k_h<<<N / 4, 256, 0, stream>>>(X, W, bias, HT, HTh);
    k_a2h<<<(N * N / 4) / 256, 256, 0, stream>>>(A, Ah);
    k_mht<<<(N / 64) * (N / 64), 256, 0, stream>>>(mh, mhT);
    k_main<<<16 * 32, 256, 0, stream>>>(mf, HT, HTh, Ah, mhT, out);
}